// Round 2
// baseline (350.047 us; speedup 1.0000x reference)
//
#include <hip/hip_runtime.h>

#define BN_EPS 1e-3f

// ---------------------------------------------------------------------------
// Submanifold 3x3x3 sparse conv: one voxel per thread, 16 fp32 accumulators.
// Weights are read straight from global memory with wave-uniform indices so
// the compiler lowers them to s_load (scalar pipe) -- no LDS at all.
// Empty neighbors are handled branchlessly (clamp index, zero via mask).
// Gathers for offset k+1 are prefetched while FMAs for offset k run.
// ---------------------------------------------------------------------------
__global__ __launch_bounds__(256)
void subm_conv_kernel(const float* __restrict__ x,    // [N,16]
                      const float* __restrict__ W,    // [27,16,16] (k,c,o)
                      const int*   __restrict__ nbr,  // [N,27], -1 = missing
                      float* __restrict__ y,          // [N,16] (pre-BN)
                      int N)
{
    int n = blockIdx.x * 256 + threadIdx.x;
    if (n >= N) return;

    float acc[16];
#pragma unroll
    for (int o = 0; o < 16; ++o) acc[o] = 0.f;

    // Preload all 27 neighbor indices (one latency hit, then register-resident)
    const int* nr = nbr + (size_t)n * 27;
    int idx[27];
#pragma unroll
    for (int k = 0; k < 27; ++k) idx[k] = nr[k];

    // Prefetch first row
    int id = idx[0];
    float mn = id >= 0 ? 1.f : 0.f;
    id = id >= 0 ? id : 0;
    const float4* xr = (const float4*)(x + (size_t)id * 16);
    float4 n0 = xr[0], n1 = xr[1], n2 = xr[2], n3 = xr[3];

#pragma unroll 1
    for (int k = 0; k < 27; ++k) {
        float4 c0 = n0, c1 = n1, c2 = n2, c3 = n3;
        float mm = mn;
        if (k < 26) {  // prefetch next gather while this k computes
            int id2 = idx[k + 1];
            mn = id2 >= 0 ? 1.f : 0.f;
            id2 = id2 >= 0 ? id2 : 0;
            const float4* xr2 = (const float4*)(x + (size_t)id2 * 16);
            n0 = xr2[0]; n1 = xr2[1]; n2 = xr2[2]; n3 = xr2[3];
        }
        float xv[16];
        xv[0]  = c0.x * mm; xv[1]  = c0.y * mm; xv[2]  = c0.z * mm; xv[3]  = c0.w * mm;
        xv[4]  = c1.x * mm; xv[5]  = c1.y * mm; xv[6]  = c1.z * mm; xv[7]  = c1.w * mm;
        xv[8]  = c2.x * mm; xv[9]  = c2.y * mm; xv[10] = c2.z * mm; xv[11] = c2.w * mm;
        xv[12] = c3.x * mm; xv[13] = c3.y * mm; xv[14] = c3.z * mm; xv[15] = c3.w * mm;

        const float* wk = W + k * 256;  // wave-uniform -> scalar loads
#pragma unroll
        for (int c = 0; c < 16; ++c) {
            float xc = xv[c];
            const float* wr = wk + c * 16;
#pragma unroll
            for (int o = 0; o < 16; ++o)
                acc[o] = fmaf(xc, wr[o], acc[o]);
        }
    }

    float4* yo = (float4*)(y + (size_t)n * 16);
    yo[0] = make_float4(acc[0],  acc[1],  acc[2],  acc[3]);
    yo[1] = make_float4(acc[4],  acc[5],  acc[6],  acc[7]);
    yo[2] = make_float4(acc[8],  acc[9],  acc[10], acc[11]);
    yo[3] = make_float4(acc[12], acc[13], acc[14], acc[15]);
}

// ---------------------------------------------------------------------------
// Per-channel sum / sumsq over y [N,16]. Grid-stride over float4s with the
// channel-group (f&3) invariant per thread; wave shuffle-reduce; LDS block
// stage; 32 atomics per block.
// ---------------------------------------------------------------------------
__global__ __launch_bounds__(256)
void stats_kernel(const float* __restrict__ y, float* __restrict__ stats, int n4)
{
    __shared__ float red[4][32];  // [wave][c(16) | 16+c]
    int tid = blockIdx.x * 256 + threadIdx.x;
    int T = gridDim.x * 256;      // multiple of 4
    float4 s = make_float4(0.f, 0.f, 0.f, 0.f);
    float4 q = make_float4(0.f, 0.f, 0.f, 0.f);
    for (int f = tid; f < n4; f += T) {
        float4 v = ((const float4*)y)[f];
        s.x += v.x; s.y += v.y; s.z += v.z; s.w += v.w;
        q.x += v.x * v.x; q.y += v.y * v.y; q.z += v.z * v.z; q.w += v.w * v.w;
    }
    // reduce across lanes with the same (lane&3)
#pragma unroll
    for (int off = 4; off <= 32; off <<= 1) {
        s.x += __shfl_down(s.x, off); s.y += __shfl_down(s.y, off);
        s.z += __shfl_down(s.z, off); s.w += __shfl_down(s.w, off);
        q.x += __shfl_down(q.x, off); q.y += __shfl_down(q.y, off);
        q.z += __shfl_down(q.z, off); q.w += __shfl_down(q.w, off);
    }
    int lane = threadIdx.x & 63, wv = threadIdx.x >> 6;
    if (lane < 4) {
        int c = lane * 4;
        red[wv][c + 0] = s.x; red[wv][c + 1] = s.y; red[wv][c + 2] = s.z; red[wv][c + 3] = s.w;
        red[wv][16 + c + 0] = q.x; red[wv][16 + c + 1] = q.y;
        red[wv][16 + c + 2] = q.z; red[wv][16 + c + 3] = q.w;
    }
    __syncthreads();
    if (threadIdx.x < 32) {
        float v = red[0][threadIdx.x] + red[1][threadIdx.x] + red[2][threadIdx.x] + red[3][threadIdx.x];
        atomicAdd(&stats[threadIdx.x], v);
    }
}

// mean/var -> scale/shift:  sc = g*rsqrt(var+eps), sh = b - mu*sc
__global__ void finalize_stats_kernel(const float* __restrict__ stats,
                                      const float* __restrict__ g,
                                      const float* __restrict__ b,
                                      float* __restrict__ ss, float invN)
{
    int o = threadIdx.x;
    if (o < 16) {
        float mu  = stats[o] * invN;
        float var = stats[16 + o] * invN - mu * mu;
        float sc  = g[o] * rsqrtf(var + BN_EPS);
        ss[o]      = sc;
        ss[16 + o] = b[o] - mu * sc;
    }
}

// z = relu(y*sc + sh), elementwise over [N,16] as float4s
__global__ __launch_bounds__(256)
void bnrelu_kernel(const float* __restrict__ y, const float* __restrict__ ss,
                   float* __restrict__ z, int n4)
{
    int f = blockIdx.x * 256 + threadIdx.x;
    if (f >= n4) return;
    int g = f & 3;
    float4 v  = ((const float4*)y)[f];
    float4 sc = ((const float4*)ss)[g];
    float4 sh = ((const float4*)(ss + 16))[g];
    float4 r;
    r.x = fmaxf(fmaf(v.x, sc.x, sh.x), 0.f);
    r.y = fmaxf(fmaf(v.y, sc.y, sh.y), 0.f);
    r.z = fmaxf(fmaf(v.z, sc.z, sh.z), 0.f);
    r.w = fmaxf(fmaf(v.w, sc.w, sh.w), 0.f);
    ((float4*)z)[f] = r;
}

// First tensor: relu(bn(y1)) -> PLAIN stores (seg is injective on rows 0..N-1:
// coords are unique, so distinct rows map to distinct unique slots).
__global__ __launch_bounds__(256)
void scatter_h_kernel(const float* __restrict__ y1, const float* __restrict__ ss,
                      const int* __restrict__ seg, float* __restrict__ merged, int N)
{
    int r = blockIdx.x * 256 + threadIdx.x;
    if (r >= N) return;
    const float4* yr = (const float4*)(y1 + (size_t)r * 16);
    float4* mo = (float4*)(merged + (size_t)seg[r] * 16);
#pragma unroll
    for (int i = 0; i < 4; ++i) {
        float4 v = yr[i];
        float4 sc = ((const float4*)ss)[i];
        float4 sh = ((const float4*)(ss + 16))[i];
        float4 rr;
        rr.x = fmaxf(fmaf(v.x, sc.x, sh.x), 0.f);
        rr.y = fmaxf(fmaf(v.y, sc.y, sh.y), 0.f);
        rr.z = fmaxf(fmaf(v.z, sc.z, sh.z), 0.f);
        rr.w = fmaxf(fmaf(v.w, sc.w, sh.w), 0.f);
        mo[i] = rr;
    }
}

// Second tensor: t2 = feat2 @ Wobo + bobo, atomically accumulated.
__global__ __launch_bounds__(256)
void scatter_t2_kernel(const float* __restrict__ feat2, const float* __restrict__ Wobo,
                       const float* __restrict__ bobo, const int* __restrict__ seg,
                       float* __restrict__ merged, int N)
{
    int r = blockIdx.x * 256 + threadIdx.x;
    if (r >= N) return;
    const float4* fr = (const float4*)(feat2 + (size_t)r * 16);
    float4 f0 = fr[0], f1 = fr[1], f2 = fr[2], f3 = fr[3];
    float fv[16];
    *(float4*)(fv + 0) = f0; *(float4*)(fv + 4) = f1;
    *(float4*)(fv + 8) = f2; *(float4*)(fv + 12) = f3;
    float v[16];
#pragma unroll
    for (int o = 0; o < 16; ++o) v[o] = bobo[o];
#pragma unroll
    for (int c = 0; c < 16; ++c) {
        float xc = fv[c];
        const float* wr = Wobo + c * 16;  // wave-uniform -> scalar loads
#pragma unroll
        for (int o = 0; o < 16; ++o) v[o] = fmaf(xc, wr[o], v[o]);
    }
    float* mo = merged + (size_t)seg[N + r] * 16;
#pragma unroll
    for (int o = 0; o < 16; ++o) atomicAdd(&mo[o], v[o]);
}

// out[u,:] = merged[u,:16] @ Wf + bf.  Block covers 256 rows; thread (j, rh)
// keeps Wf[:,j] in 16 registers and loops 128 rows; merged row loads are
// wave-uniform (L1 broadcast); stores are fully coalesced.
__global__ __launch_bounds__(256)
void final_gemm_kernel(const float* __restrict__ merged, const float* __restrict__ Wf,
                       const float* __restrict__ bf, float* __restrict__ out, int U)
{
    int j  = threadIdx.x & 127;
    int rh = threadIdx.x >> 7;
    int u0 = blockIdx.x * 256 + rh * 128;
    if (u0 >= U) return;
    float wj[16];
#pragma unroll
    for (int c = 0; c < 16; ++c) wj[c] = Wf[c * 128 + j];
    float bj = bf[j];
    int rend = min(u0 + 128, U);

    const float4* mr = (const float4*)(merged + (size_t)u0 * 16);
    float4 a0 = mr[0], a1 = mr[1], a2 = mr[2], a3 = mr[3];
#pragma unroll 1
    for (int u = u0; u < rend; ++u) {
        float4 c0 = a0, c1 = a1, c2 = a2, c3 = a3;
        if (u + 1 < rend) {
            const float4* nx = (const float4*)(merged + (size_t)(u + 1) * 16);
            a0 = nx[0]; a1 = nx[1]; a2 = nx[2]; a3 = nx[3];
        }
        float s = bj;
        s = fmaf(c0.x, wj[0],  s); s = fmaf(c0.y, wj[1],  s);
        s = fmaf(c0.z, wj[2],  s); s = fmaf(c0.w, wj[3],  s);
        s = fmaf(c1.x, wj[4],  s); s = fmaf(c1.y, wj[5],  s);
        s = fmaf(c1.z, wj[6],  s); s = fmaf(c1.w, wj[7],  s);
        s = fmaf(c2.x, wj[8],  s); s = fmaf(c2.y, wj[9],  s);
        s = fmaf(c2.z, wj[10], s); s = fmaf(c2.w, wj[11], s);
        s = fmaf(c3.x, wj[12], s); s = fmaf(c3.y, wj[13], s);
        s = fmaf(c3.z, wj[14], s); s = fmaf(c3.w, wj[15], s);
        out[(size_t)u * 128 + j] = s;
    }
}

extern "C" void kernel_launch(void* const* d_in, const int* in_sizes, int n_in,
                              void* d_out, int out_size, void* d_ws, size_t ws_size,
                              hipStream_t stream)
{
    const float* vf    = (const float*)d_in[0];
    const float* feat2 = (const float*)d_in[1];
    const float* W0    = (const float*)d_in[2];
    const float* g0    = (const float*)d_in[3];
    const float* b0    = (const float*)d_in[4];
    const float* W1    = (const float*)d_in[5];
    const float* g1    = (const float*)d_in[6];
    const float* b1    = (const float*)d_in[7];
    const float* Wobo  = (const float*)d_in[8];
    const float* bobo  = (const float*)d_in[9];
    const float* Wf    = (const float*)d_in[10];
    const float* bf    = (const float*)d_in[11];
    const int*   nbr   = (const int*)d_in[12];
    const int*   seg   = (const int*)d_in[13];

    int N = in_sizes[0] / 16;   // 100000
    int U = out_size / 128;     // num_segments

    float* out = (float*)d_out;
    float* ws  = (float*)d_ws;

    // Workspace layout (floats):
    float* y0raw  = ws;                        // N*16
    float* xp1    = ws + (size_t)N * 16;       // N*16 (relu(bn(y0)))
    float* y1raw  = ws + (size_t)2 * N * 16;   // N*16
    float* stats  = ws + (size_t)3 * N * 16;   // 64 (stats0 | stats1)
    float* ssb    = stats + 64;                // 64 (ss0 | ss1)
    float* merged = ssb + 64;                  // U*16

    hipMemsetAsync(stats, 0, 64 * sizeof(float), stream);
    hipMemsetAsync(merged, 0, (size_t)U * 16 * sizeof(float), stream);

    int gbN = (N + 255) / 256;
    int n4  = N * 4;
    int gb4 = (n4 + 255) / 256;

    subm_conv_kernel<<<gbN, 256, 0, stream>>>(vf, W0, nbr, y0raw, N);
    stats_kernel<<<256, 256, 0, stream>>>(y0raw, stats, n4);
    finalize_stats_kernel<<<1, 64, 0, stream>>>(stats, g0, b0, ssb, 1.f / N);
    bnrelu_kernel<<<gb4, 256, 0, stream>>>(y0raw, ssb, xp1, n4);

    subm_conv_kernel<<<gbN, 256, 0, stream>>>(xp1, W1, nbr, y1raw, N);
    stats_kernel<<<256, 256, 0, stream>>>(y1raw, stats + 32, n4);
    finalize_stats_kernel<<<1, 64, 0, stream>>>(stats + 32, g1, b1, ssb + 32, 1.f / N);

    scatter_h_kernel<<<gbN, 256, 0, stream>>>(y1raw, ssb + 32, seg, merged, N);
    scatter_t2_kernel<<<gbN, 256, 0, stream>>>(feat2, Wobo, bobo, seg, merged, N);
    final_gemm_kernel<<<(U + 255) / 256, 256, 0, stream>>>(merged, Wf, bf, out, U);
}